// Round 3
// baseline (10370.985 us; speedup 1.0000x reference)
//
#include <hip/hip_runtime.h>
#include <math.h>

// Problem constants
#define B_    256
#define NPTS  1024
#define T_    50

// ---------------------------------------------------------------------------
// ws layout (bytes):
//   [0,       786432)   whT  f32 [256][768]   (W_hh transposed)
//   [786432,  1310720)  hmax u32 [256][512]   (f32-bit maxpool via atomicMax)
// total 1.25 MB
// ---------------------------------------------------------------------------

__global__ __launch_bounds__(256) void prep_kernel(const float* __restrict__ whh,
                                                   float* __restrict__ whT,
                                                   unsigned* __restrict__ hmax) {
  int idx = blockIdx.x * 256 + threadIdx.x;   // grid 768*256 = 196608
  if (idx < 196608) {
    int k = idx / 768;
    int o = idx - k * 768;
    whT[idx] = whh[o * 256 + k];              // whT[k][o] = W_hh[o][k]
  }
  if (idx < 131072) hmax[idx] = 0u;           // bits 0 == +0.0f; relu>=0 valid
}

// ---------------------------------------------------------------------------
// Encoder, f32: per-point MLP 3->64->128->512 (relu) + max-pool over ALL
// 1024 points. Each thread computes ALL 512 layer-3 channels for its point
// (round-2 bug: each wave pooled only its own 64 points for its channel
// slice). Wave shuffle-max -> per-wave LDS slot (written exactly once per
// (wave,channel): no init, no race) -> block reduce -> global atomicMax on
// f32 bits across the 4 blocks per batch.
// ---------------------------------------------------------------------------
__global__ __launch_bounds__(256, 2) void enc_kernel(
    const float* __restrict__ data,
    const float* __restrict__ w1, const float* __restrict__ b1,
    const float* __restrict__ w2, const float* __restrict__ b2,
    const float* __restrict__ w3, const float* __restrict__ b3,
    unsigned* __restrict__ hmax) {
  __shared__ float slot_l[4 * 512];           // [wave][channel]
  const int tid = threadIdx.x;
  const int b = blockIdx.x >> 2;
  const int p = ((blockIdx.x & 3) << 8) + tid;
  const int gp = (b * NPTS + p) * 3;
  const float x0 = data[gp], x1 = data[gp + 1], x2 = data[gp + 2];

  // layers 1+2 fused: h2 accumulates while h1[j] is produced and discarded
  float h2[128];
#pragma unroll
  for (int k = 0; k < 128; ++k) h2[k] = b2[k];
#pragma unroll 1
  for (int j = 0; j < 64; ++j) {
    float hj = fmaf(x0, w1[j], fmaf(x1, w1[64 + j], fmaf(x2, w1[128 + j], b1[j])));
    hj = fmaxf(hj, 0.0f);
    const float* __restrict__ w2r = w2 + j * 128;   // uniform -> s_load
#pragma unroll
    for (int k = 0; k < 128; ++k) h2[k] = fmaf(hj, w2r[k], h2[k]);
  }
#pragma unroll
  for (int k = 0; k < 128; ++k) h2[k] = fmaxf(h2[k], 0.0f);

  // layer 3: ALL 512 outputs per thread, 32 chunks of 16; pool over the wave
  const int lane = tid & 63;
  const int wave = tid >> 6;
#pragma unroll 1
  for (int oc = 0; oc < 32; ++oc) {
    const int o0 = oc * 16;                         // uniform across block
    float acc[16];
#pragma unroll
    for (int j = 0; j < 16; ++j) acc[j] = b3[o0 + j];
#pragma unroll
    for (int k = 0; k < 128; ++k) {
      const float hk = h2[k];
      const float* __restrict__ w3r = w3 + k * 512 + o0;  // uniform -> s_load
#pragma unroll
      for (int j = 0; j < 16; ++j) acc[j] = fmaf(hk, w3r[j], acc[j]);
    }
#pragma unroll
    for (int j = 0; j < 16; ++j) {
      float v = fmaxf(acc[j], 0.0f);                // relu, then pool
#pragma unroll
      for (int off = 32; off > 0; off >>= 1)
        v = fmaxf(v, __shfl_xor(v, off, 64));
      if (lane == 0) slot_l[(wave << 9) + o0 + j] = v;    // once per (wave,ch)
    }
  }
  __syncthreads();
  for (int o = tid; o < 512; o += 256) {
    const float m = fmaxf(fmaxf(slot_l[o], slot_l[512 + o]),
                          fmaxf(slot_l[1024 + o], slot_l[1536 + o]));
    atomicMax(hmax + (b << 9) + o, __float_as_uint(m));   // nonneg: bits monotone
  }
}

// ---------------------------------------------------------------------------
// GRU rollout (+ init MLP fused), f64 internal, h state in LDS (barrier-
// coherent, no cache games). One block = 2 samples (G=2), 768 threads
// (thread t = gate-output o), 128 blocks.
// ---------------------------------------------------------------------------
__global__ __launch_bounds__(768) void gru_kernel(
    const float* __restrict__ henc,     // [256][512] f32 (maxpool bits)
    const float* __restrict__ mw1, const float* __restrict__ mb1,
    const float* __restrict__ mw2, const float* __restrict__ mb2,
    const float* __restrict__ mw3, const float* __restrict__ mb3,
    const float* __restrict__ wih, const float* __restrict__ whT,
    const float* __restrict__ bih, const float* __restrict__ bhh,
    const float* __restrict__ ow1, const float* __restrict__ ob1,
    const float* __restrict__ ow2, const float* __restrict__ ob2,
    const float* __restrict__ ow3, const float* __restrict__ ob3,
    float* __restrict__ dout) {
  __shared__ double h_l[256 * 2];      // hidden state, [k][g]
  __shared__ double comb_l[768 * 2];   // gi+gh (r,z) / gh (n), [o][g]
  __shared__ double gin_l[256 * 2];    // i_n, [i][g]
  __shared__ double g1_l[256 * 2];
  __shared__ double g2_l[128 * 2];
  __shared__ double o1_l[64 * 2];
  __shared__ double o2_l[64 * 2];
  __shared__ double gia_l[12];         // gi accumulator, [g][c]

  const int t = threadIdx.x;
  const int s0 = blockIdx.x << 1;

  // ---- phase 0: gru_h init MLP (512->256->128->256), f64 ----
  if (t < 512) {
    const int o = t & 255, g = t >> 8;                    // g wave-uniform
    const float* __restrict__ hrow = henc + ((s0 + g) << 9);
    double a = (double)mb1[o];
#pragma unroll 4
    for (int k = 0; k < 512; ++k)
      a = fma((double)hrow[k], (double)mw1[k * 256 + o], a);
    g1_l[o * 2 + g] = fmax(a, 0.0);
  }
  __syncthreads();
  if (t < 256) {
    const int o = t & 127, g = t >> 7;
    double a = (double)mb2[o];
#pragma unroll 4
    for (int k = 0; k < 256; ++k) a = fma(g1_l[k * 2 + g], (double)mw2[k * 128 + o], a);
    g2_l[o * 2 + g] = fmax(a, 0.0);
  }
  __syncthreads();
  if (t < 512) {
    const int o = t & 255, g = t >> 8;
    double a = (double)mb3[o];
#pragma unroll 4
    for (int k = 0; k < 128; ++k) a = fma(g2_l[k * 2 + g], (double)mw3[k * 256 + o], a);
    h_l[o * 2 + g] = a;                                   // no relu on final
  }
  if (t < 12) gia_l[t] = 0.0;
  __syncthreads();

  // hoisted per-thread constants (o = t fixed across steps)
  const int o = t;
  const double bhh_o = (double)bhh[o];
  const double bih_o = (double)bih[o];
  double wo[6];
#pragma unroll
  for (int a = 0; a < 6; ++a) wo[a] = (double)wih[o * 6 + a];
  const float* __restrict__ wcol = whT + o;

  for (int step = 0; step < T_; ++step) {
    // ---- phase 1: gi (6-dot) + gh matvec (len-256 dot, W shared by g) ----
    double gi0 = bih_o, gi1 = bih_o;
#pragma unroll
    for (int a = 0; a < 6; ++a) {
      gi0 = fma(wo[a], gia_l[a], gi0);
      gi1 = fma(wo[a], gia_l[6 + a], gi1);
    }
    double acc0, acc1;
    if (o < 512) {          // r,z gates: gi and gh just add -> combine now
      acc0 = bhh_o + gi0; acc1 = bhh_o + gi1;
    } else {                // n gate: keep i_n separate (r scales h_n only)
      acc0 = bhh_o; acc1 = bhh_o;
      gin_l[(o - 512) * 2 + 0] = gi0; gin_l[(o - 512) * 2 + 1] = gi1;
    }
#pragma unroll 4
    for (int k = 0; k < 256; ++k) {
      const double w = (double)wcol[k * 768];             // coalesced f32 load
      const double2 h2v = *(const double2*)(h_l + (k << 1)); // LDS broadcast
      acc0 = fma(h2v.x, w, acc0);
      acc1 = fma(h2v.y, w, acc1);
    }
    comb_l[o * 2 + 0] = acc0; comb_l[o * 2 + 1] = acc1;
    __syncthreads();

    // ---- phase 2: gate math + h update, f64 ----
    if (t < 512) {
      const int i = t & 255, g = t >> 8;
      const double rv = 1.0 / (1.0 + exp(-comb_l[i * 2 + g]));
      const double zv = 1.0 / (1.0 + exp(-comb_l[(256 + i) * 2 + g]));
      const double nv = tanh(fma(rv, comb_l[(512 + i) * 2 + g], gin_l[i * 2 + g]));
      const double hp = h_l[i * 2 + g];
      h_l[i * 2 + g] = fma(zv, hp - nv, nv);              // (1-z)n + z*hp
    }
    __syncthreads();

    // ---- phase 3: out_mlp 256->64->64->6 + output writes, f64 ----
    if (t < 128) {
      const int j = t & 63, g = (t >> 6) & 1;             // g wave-uniform
      double a = (double)ob1[j];
#pragma unroll 4
      for (int k = 0; k < 256; ++k) a = fma(h_l[k * 2 + g], (double)ow1[k * 64 + j], a);
      o1_l[j * 2 + g] = fmax(a, 0.0);
    }
    __syncthreads();
    if (t < 128) {
      const int j = t & 63, g = (t >> 6) & 1;
      double a = (double)ob2[j];
#pragma unroll 4
      for (int k = 0; k < 64; ++k) a = fma(o1_l[k * 2 + g], (double)ow2[k * 64 + j], a);
      o2_l[j * 2 + g] = fmax(a, 0.0);
    }
    __syncthreads();
    if (t < 12) {
      const int g = t / 6, c = t - g * 6;
      double a = (double)ob3[c];
#pragma unroll 4
      for (int k = 0; k < 64; ++k) a = fma(o2_l[k * 2 + g], (double)ow3[k * 6 + c], a);
      const double gi_new = gia_l[g * 6 + c] + a;
      gia_l[g * 6 + c] = gi_new;
      const int s = s0 + g;
      dout[s * 300 + step * 6 + c] = (float)a;              // dws
      dout[76800 + s * 300 + step * 6 + c] = (float)gi_new; // ws (post-update)
    }
    __syncthreads();
  }
}

extern "C" void kernel_launch(void* const* d_in, const int* in_sizes, int n_in,
                              void* d_out, int out_size, void* d_ws, size_t ws_size,
                              hipStream_t stream) {
  const float* data = (const float*)d_in[0];
  // d_in[1] = horizon (always 50)
  const float* ew1 = (const float*)d_in[2];
  const float* eb1 = (const float*)d_in[3];
  const float* ew2 = (const float*)d_in[4];
  const float* eb2 = (const float*)d_in[5];
  const float* ew3 = (const float*)d_in[6];
  const float* eb3 = (const float*)d_in[7];
  const float* mw1 = (const float*)d_in[8];
  const float* mb1 = (const float*)d_in[9];
  const float* mw2 = (const float*)d_in[10];
  const float* mb2 = (const float*)d_in[11];
  const float* mw3 = (const float*)d_in[12];
  const float* mb3 = (const float*)d_in[13];
  const float* wih = (const float*)d_in[14];
  const float* whh = (const float*)d_in[15];
  const float* bih = (const float*)d_in[16];
  const float* bhh = (const float*)d_in[17];
  const float* ow1 = (const float*)d_in[18];
  const float* ob1 = (const float*)d_in[19];
  const float* ow2 = (const float*)d_in[20];
  const float* ob2 = (const float*)d_in[21];
  const float* ow3 = (const float*)d_in[22];
  const float* ob3 = (const float*)d_in[23];
  float* out = (float*)d_out;

  char* ws = (char*)d_ws;
  float*    whT  = (float*)(ws);                // 786432 B
  unsigned* hmax = (unsigned*)(ws + 786432);    // 524288 B -> end 1310720

  prep_kernel<<<768, 256, 0, stream>>>(whh, whT, hmax);
  enc_kernel<<<1024, 256, 0, stream>>>(data, ew1, eb1, ew2, eb2, ew3, eb3, hmax);
  gru_kernel<<<128, 768, 0, stream>>>((const float*)hmax,
                                      mw1, mb1, mw2, mb2, mw3, mb3,
                                      wih, whT, bih, bhh,
                                      ow1, ob1, ow2, ob2, ow3, ob3,
                                      out);
}

// Round 4
// 3350.993 us; speedup vs baseline: 3.0949x; 3.0949x over previous
//
#include <hip/hip_runtime.h>
#include <math.h>

// Problem constants
#define B_    256
#define NPTS  1024
#define T_    50

// ---------------------------------------------------------------------------
// ws layout (bytes):
//   [0,       786432)   whT  f32 [256][768]   (W_hh transposed)
//   [786432,  1310720)  henc f32 [256][512]   (encoder output)
// ---------------------------------------------------------------------------

__global__ __launch_bounds__(256) void prep_kernel(const float* __restrict__ whh,
                                                   float* __restrict__ whT) {
  int idx = blockIdx.x * 256 + threadIdx.x;   // grid 768*256 = 196608
  if (idx < 196608) {
    int k = idx / 768;
    int o = idx - k * 768;
    whT[idx] = whh[o * 256 + k];              // whT[k][o] = W_hh[o][k]
  }
}

// ---------------------------------------------------------------------------
// Fused encoder: one block per batch sample (grid 256 = 1/CU), 1024 threads.
// Per 32-point tile: layers 1+2 staged into LDS h2t[128][33] (pad 33 ->
// conflict-free reads), then layer 3 as a register-tiled GEMM with fused
// max-pool. NO per-thread array exceeds 16 floats (round-3 spill: h2[128]
// stayed in scratch -> 481 MB WRITE_SIZE, 9.2 ms).
// Accumulation orders are bit-identical to round 3's passing kernel.
// ---------------------------------------------------------------------------
__global__ __launch_bounds__(1024, 4) void enc_kernel(
    const float* __restrict__ data,
    const float* __restrict__ w1, const float* __restrict__ b1,
    const float* __restrict__ w2, const float* __restrict__ b2,
    const float* __restrict__ w3, const float* __restrict__ b3,
    float* __restrict__ henc) {
  __shared__ float h2t[128][33];
  const int t = threadIdx.x;
  const int b = blockIdx.x;
  // GEMM role: thread = (out-group og, point-lane pl); wave = 2 og x 32 pl
  const int pl = t & 31, og = t >> 5;
  // staging role: thread = (channel-quad scq, point spt)
  const int spt = t & 31, scq = t >> 5;

  const float4 b3r0 = *(const float4*)(b3 + og * 16 + 0);
  const float4 b3r1 = *(const float4*)(b3 + og * 16 + 4);
  const float4 b3r2 = *(const float4*)(b3 + og * 16 + 8);
  const float4 b3r3 = *(const float4*)(b3 + og * 16 + 12);
  float4 m0 = {0, 0, 0, 0}, m1 = {0, 0, 0, 0}, m2 = {0, 0, 0, 0}, m3 = {0, 0, 0, 0};

#pragma unroll 1
  for (int tile = 0; tile < 32; ++tile) {
    // ---- stage: layers 1+2 for 32 points -> LDS (thread: 4 channels) ----
    {
      const int ptg = b * NPTS + tile * 32 + spt;
      const float x0 = data[ptg * 3], x1 = data[ptg * 3 + 1], x2 = data[ptg * 3 + 2];
      float a0 = b2[scq * 4], a1 = b2[scq * 4 + 1],
            a2 = b2[scq * 4 + 2], a3 = b2[scq * 4 + 3];
#pragma unroll 4
      for (int j = 0; j < 64; ++j) {
        float hj = fmaf(x0, w1[j], fmaf(x1, w1[64 + j], fmaf(x2, w1[128 + j], b1[j])));
        hj = fmaxf(hj, 0.0f);
        const float4 wv = *(const float4*)(w2 + j * 128 + scq * 4); // lane-shared
        a0 = fmaf(hj, wv.x, a0); a1 = fmaf(hj, wv.y, a1);
        a2 = fmaf(hj, wv.z, a2); a3 = fmaf(hj, wv.w, a3);
      }
      h2t[scq * 4 + 0][spt] = fmaxf(a0, 0.0f);
      h2t[scq * 4 + 1][spt] = fmaxf(a1, 0.0f);
      h2t[scq * 4 + 2][spt] = fmaxf(a2, 0.0f);
      h2t[scq * 4 + 3][spt] = fmaxf(a3, 0.0f);
    }
    __syncthreads();

    // ---- layer-3 GEMM: 1 point x 16 outs per thread, k = 0..127 ----
    float4 c0 = b3r0, c1 = b3r1, c2 = b3r2, c3 = b3r3;
#pragma unroll 2
    for (int k = 0; k < 128; ++k) {
      const float hk = h2t[k][pl];                         // bank = pl: free
      const float* __restrict__ w3r = w3 + k * 512 + og * 16;
      const float4 wa = *(const float4*)(w3r + 0);
      const float4 wb = *(const float4*)(w3r + 4);
      const float4 wc = *(const float4*)(w3r + 8);
      const float4 wd = *(const float4*)(w3r + 12);
      c0.x = fmaf(hk, wa.x, c0.x); c0.y = fmaf(hk, wa.y, c0.y);
      c0.z = fmaf(hk, wa.z, c0.z); c0.w = fmaf(hk, wa.w, c0.w);
      c1.x = fmaf(hk, wb.x, c1.x); c1.y = fmaf(hk, wb.y, c1.y);
      c1.z = fmaf(hk, wb.z, c1.z); c1.w = fmaf(hk, wb.w, c1.w);
      c2.x = fmaf(hk, wc.x, c2.x); c2.y = fmaf(hk, wc.y, c2.y);
      c2.z = fmaf(hk, wc.z, c2.z); c2.w = fmaf(hk, wc.w, c2.w);
      c3.x = fmaf(hk, wd.x, c3.x); c3.y = fmaf(hk, wd.y, c3.y);
      c3.z = fmaf(hk, wd.z, c3.z); c3.w = fmaf(hk, wd.w, c3.w);
    }
    m0.x = fmaxf(m0.x, c0.x); m0.y = fmaxf(m0.y, c0.y);
    m0.z = fmaxf(m0.z, c0.z); m0.w = fmaxf(m0.w, c0.w);
    m1.x = fmaxf(m1.x, c1.x); m1.y = fmaxf(m1.y, c1.y);
    m1.z = fmaxf(m1.z, c1.z); m1.w = fmaxf(m1.w, c1.w);
    m2.x = fmaxf(m2.x, c2.x); m2.y = fmaxf(m2.y, c2.y);
    m2.z = fmaxf(m2.z, c2.z); m2.w = fmaxf(m2.w, c2.w);
    m3.x = fmaxf(m3.x, c3.x); m3.y = fmaxf(m3.y, c3.y);
    m3.z = fmaxf(m3.z, c3.z); m3.w = fmaxf(m3.w, c3.w);
    __syncthreads();                                       // h2t reuse guard
  }

  // ---- pool across the 32 point-lanes (xor 1..16 stays inside half-wave) --
#pragma unroll
  for (int off = 16; off > 0; off >>= 1) {
    m0.x = fmaxf(m0.x, __shfl_xor(m0.x, off, 64)); m0.y = fmaxf(m0.y, __shfl_xor(m0.y, off, 64));
    m0.z = fmaxf(m0.z, __shfl_xor(m0.z, off, 64)); m0.w = fmaxf(m0.w, __shfl_xor(m0.w, off, 64));
    m1.x = fmaxf(m1.x, __shfl_xor(m1.x, off, 64)); m1.y = fmaxf(m1.y, __shfl_xor(m1.y, off, 64));
    m1.z = fmaxf(m1.z, __shfl_xor(m1.z, off, 64)); m1.w = fmaxf(m1.w, __shfl_xor(m1.w, off, 64));
    m2.x = fmaxf(m2.x, __shfl_xor(m2.x, off, 64)); m2.y = fmaxf(m2.y, __shfl_xor(m2.y, off, 64));
    m2.z = fmaxf(m2.z, __shfl_xor(m2.z, off, 64)); m2.w = fmaxf(m2.w, __shfl_xor(m2.w, off, 64));
    m3.x = fmaxf(m3.x, __shfl_xor(m3.x, off, 64)); m3.y = fmaxf(m3.y, __shfl_xor(m3.y, off, 64));
    m3.z = fmaxf(m3.z, __shfl_xor(m3.z, off, 64)); m3.w = fmaxf(m3.w, __shfl_xor(m3.w, off, 64));
  }
  if (pl == 0) {                       // one block owns the batch: plain store
    float* __restrict__ hr = henc + b * 512 + og * 16;
    *(float4*)(hr + 0) = m0; *(float4*)(hr + 4) = m1;
    *(float4*)(hr + 8) = m2; *(float4*)(hr + 12) = m3;
  }
}

// ---------------------------------------------------------------------------
// GRU rollout, f64 internal, h in LDS. Block = 2 samples, 1024 threads:
// after each h-update, waves 0-11 (t<768) compute next step's W_hh@h matvec
// (3 barrier-chunks, acc carried in regs) CONCURRENTLY with waves 12-15
// running the out_mlp stages — both depend only on the new h. The tiny
// gi = bih + W_ih@gia 6-dot folds into the gate stage.
// All f64 dot-products keep round-3's accumulation order (ref-validated).
// ---------------------------------------------------------------------------
__global__ __launch_bounds__(1024) void gru_kernel(
    const float* __restrict__ henc,     // [256][512]
    const float* __restrict__ mw1, const float* __restrict__ mb1,
    const float* __restrict__ mw2, const float* __restrict__ mb2,
    const float* __restrict__ mw3, const float* __restrict__ mb3,
    const float* __restrict__ wih, const float* __restrict__ whT,
    const float* __restrict__ bih, const float* __restrict__ bhh,
    const float* __restrict__ ow1, const float* __restrict__ ob1,
    const float* __restrict__ ow2, const float* __restrict__ ob2,
    const float* __restrict__ ow3, const float* __restrict__ ob3,
    float* __restrict__ dout) {
  __shared__ __align__(16) double h_l[256 * 2];   // [i][g]
  __shared__ double comb_l[768 * 2];   // bhh + Whh@h, [o][g]
  __shared__ double g1_l[256 * 2];
  __shared__ double g2_l[128 * 2];
  __shared__ double o1_l[64 * 2];
  __shared__ double o2_l[64 * 2];
  __shared__ double gia_l[12];         // gi accumulator, [g][c]
  __shared__ float wih_l[768 * 6];
  __shared__ float bih_l[768];

  const int t = threadIdx.x;
  const int s0 = blockIdx.x << 1;

  for (int i = t; i < 768 * 6; i += 1024) wih_l[i] = wih[i];
  if (t < 768) bih_l[t] = bih[t];

  // ---- phase 0: gru_h init MLP (512->256->128->256), f64 ----
  if (t < 512) {
    const int o = t & 255, g = t >> 8;
    const float* __restrict__ hrow = henc + ((s0 + g) << 9);
    double a = (double)mb1[o];
#pragma unroll 4
    for (int k = 0; k < 512; ++k)
      a = fma((double)hrow[k], (double)mw1[k * 256 + o], a);
    g1_l[o * 2 + g] = fmax(a, 0.0);
  }
  __syncthreads();
  if (t < 256) {
    const int o = t & 127, g = t >> 7;
    double a = (double)mb2[o];
#pragma unroll 4
    for (int k = 0; k < 256; ++k) a = fma(g1_l[k * 2 + g], (double)mw2[k * 128 + o], a);
    g2_l[o * 2 + g] = fmax(a, 0.0);
  }
  __syncthreads();
  if (t < 512) {
    const int o = t & 255, g = t >> 8;
    double a = (double)mb3[o];
#pragma unroll 4
    for (int k = 0; k < 128; ++k) a = fma(g2_l[k * 2 + g], (double)mw3[k * 256 + o], a);
    h_l[o * 2 + g] = a;
  }
  if (t < 12) gia_l[t] = 0.0;
  __syncthreads();

  // per-matvec-thread constants
  const double bhh_o = (t < 768) ? (double)bhh[t] : 0.0;
  const float* __restrict__ wcol = whT + (t < 768 ? t : 0);
  const int tb = t - 768;

  // ---- prologue: comb = bhh + Whh @ h0 ----
  if (t < 768) {
    double a0 = bhh_o, a1 = bhh_o;
#pragma unroll 4
    for (int k = 0; k < 256; ++k) {
      const double w = (double)wcol[k * 768];
      const double2 hv = *(const double2*)(h_l + (k << 1));
      a0 = fma(hv.x, w, a0); a1 = fma(hv.y, w, a1);
    }
    comb_l[t * 2 + 0] = a0; comb_l[t * 2 + 1] = a1;
  }
  __syncthreads();

  for (int step = 0; step < T_; ++step) {
    // ---- G: gates + h update (t<512); gi 6-dot folded in ----
    if (t < 512) {
      const int i = t & 255, g = t >> 8;
      double gr = (double)bih_l[i], gz = (double)bih_l[256 + i],
             gn = (double)bih_l[512 + i];
#pragma unroll
      for (int a = 0; a < 6; ++a) {
        const double xa = gia_l[g * 6 + a];
        gr = fma((double)wih_l[i * 6 + a], xa, gr);
        gz = fma((double)wih_l[(256 + i) * 6 + a], xa, gz);
        gn = fma((double)wih_l[(512 + i) * 6 + a], xa, gn);
      }
      const double rv = 1.0 / (1.0 + exp(-(comb_l[i * 2 + g] + gr)));
      const double zv = 1.0 / (1.0 + exp(-(comb_l[(256 + i) * 2 + g] + gz)));
      const double nv = tanh(fma(rv, comb_l[(512 + i) * 2 + g], gn));
      const double hp = h_l[i * 2 + g];
      h_l[i * 2 + g] = fma(zv, hp - nv, nv);
    }
    __syncthreads();

    // ---- C1/C2/C3: matvec chunks (t<768) || out_mlp stages (t>=768) ----
    double a0 = bhh_o, a1 = bhh_o;
    if (t < 768) {
#pragma unroll 4
      for (int k = 0; k < 86; ++k) {
        const double w = (double)wcol[k * 768];
        const double2 hv = *(const double2*)(h_l + (k << 1));
        a0 = fma(hv.x, w, a0); a1 = fma(hv.y, w, a1);
      }
    } else if (tb < 128) {             // out_mlp layer 1 (h -> 64)
      const int j = tb & 63, g = tb >> 6;
      double a = (double)ob1[j];
#pragma unroll 4
      for (int k = 0; k < 256; ++k) a = fma(h_l[k * 2 + g], (double)ow1[k * 64 + j], a);
      o1_l[j * 2 + g] = fmax(a, 0.0);
    }
    __syncthreads();

    if (t < 768) {
#pragma unroll 4
      for (int k = 86; k < 171; ++k) {
        const double w = (double)wcol[k * 768];
        const double2 hv = *(const double2*)(h_l + (k << 1));
        a0 = fma(hv.x, w, a0); a1 = fma(hv.y, w, a1);
      }
    } else if (tb < 128) {             // out_mlp layer 2 (64 -> 64)
      const int j = tb & 63, g = tb >> 6;
      double a = (double)ob2[j];
#pragma unroll 4
      for (int k = 0; k < 64; ++k) a = fma(o1_l[k * 2 + g], (double)ow2[k * 64 + j], a);
      o2_l[j * 2 + g] = fmax(a, 0.0);
    }
    __syncthreads();

    if (t < 768) {
#pragma unroll 4
      for (int k = 171; k < 256; ++k) {
        const double w = (double)wcol[k * 768];
        const double2 hv = *(const double2*)(h_l + (k << 1));
        a0 = fma(hv.x, w, a0); a1 = fma(hv.y, w, a1);
      }
      comb_l[t * 2 + 0] = a0; comb_l[t * 2 + 1] = a1;
    } else if (tb < 12) {              // out_mlp layer 3 + gia + stores
      const int g = tb / 6, c = tb - g * 6;
      double a = (double)ob3[c];
#pragma unroll 4
      for (int k = 0; k < 64; ++k) a = fma(o2_l[k * 2 + g], (double)ow3[k * 6 + c], a);
      const double gi_new = gia_l[g * 6 + c] + a;
      gia_l[g * 6 + c] = gi_new;
      const int s = s0 + g;
      dout[s * 300 + step * 6 + c] = (float)a;              // dws
      dout[76800 + s * 300 + step * 6 + c] = (float)gi_new; // ws
    }
    __syncthreads();
  }
}

extern "C" void kernel_launch(void* const* d_in, const int* in_sizes, int n_in,
                              void* d_out, int out_size, void* d_ws, size_t ws_size,
                              hipStream_t stream) {
  const float* data = (const float*)d_in[0];
  // d_in[1] = horizon (always 50)
  const float* ew1 = (const float*)d_in[2];
  const float* eb1 = (const float*)d_in[3];
  const float* ew2 = (const float*)d_in[4];
  const float* eb2 = (const float*)d_in[5];
  const float* ew3 = (const float*)d_in[6];
  const float* eb3 = (const float*)d_in[7];
  const float* mw1 = (const float*)d_in[8];
  const float* mb1 = (const float*)d_in[9];
  const float* mw2 = (const float*)d_in[10];
  const float* mb2 = (const float*)d_in[11];
  const float* mw3 = (const float*)d_in[12];
  const float* mb3 = (const float*)d_in[13];
  const float* wih = (const float*)d_in[14];
  const float* whh = (const float*)d_in[15];
  const float* bih = (const float*)d_in[16];
  const float* bhh = (const float*)d_in[17];
  const float* ow1 = (const float*)d_in[18];
  const float* ob1 = (const float*)d_in[19];
  const float* ow2 = (const float*)d_in[20];
  const float* ob2 = (const float*)d_in[21];
  const float* ow3 = (const float*)d_in[22];
  const float* ob3 = (const float*)d_in[23];
  float* out = (float*)d_out;

  char* ws = (char*)d_ws;
  float* whT  = (float*)(ws);                // 786432 B
  float* henc = (float*)(ws + 786432);       // 524288 B -> end 1310720

  prep_kernel<<<768, 256, 0, stream>>>(whh, whT);
  enc_kernel<<<256, 1024, 0, stream>>>(data, ew1, eb1, ew2, eb2, ew3, eb3, henc);
  gru_kernel<<<128, 1024, 0, stream>>>(henc,
                                       mw1, mb1, mw2, mb2, mw3, mb3,
                                       wih, whT, bih, bhh,
                                       ow1, ob1, ow2, ob2, ow3, ob3,
                                       out);
}

// Round 5
// 2253.628 us; speedup vs baseline: 4.6019x; 1.4869x over previous
//
#include <hip/hip_runtime.h>
#include <math.h>

// Problem constants
#define B_    256
#define NPTS  1024
#define T_    50

// ---------------------------------------------------------------------------
// ws layout: [0, 524288) henc f32 [256][512]
// ---------------------------------------------------------------------------

// ---------------------------------------------------------------------------
// Fused encoder: block = 1 sample, 1024 threads = 16 waves.
// Wave w owns the wave-UNIFORM output slice [32w, 32w+32) -> all weight
// reads are scalar s_loads (SMEM path), fixing round 4's VMEM-issue bound
// (VALUBusy 17%: ~262k same-address vector loads per CU). Tile = 64 points
// staged to LDS h2t[128][66] (64+2 pad; lane-indexed reads = 2-way = free).
// Math: identical fma/accumulation order to rounds 3/4 (ref-validated);
// maxpool-with-0-init implements the layer-3 relu.
// ---------------------------------------------------------------------------
__global__ __launch_bounds__(1024, 4) void enc_kernel(
    const float* __restrict__ data,
    const float* __restrict__ w1, const float* __restrict__ b1,
    const float* __restrict__ w2, const float* __restrict__ b2,
    const float* __restrict__ w3, const float* __restrict__ b3,
    float* __restrict__ henc) {
  __shared__ float h2t[128][66];
  const int t = threadIdx.x;
  const int b = blockIdx.x;
  const int lane = t & 63;
  const int wv = __builtin_amdgcn_readfirstlane(t >> 6);   // wave id 0..15

  float m[32];
#pragma unroll
  for (int o = 0; o < 32; ++o) m[o] = 0.0f;                // relu via max w/ 0
  const float* __restrict__ w3b = w3 + wv * 32;

#pragma unroll 1
  for (int tile = 0; tile < 16; ++tile) {
    // ---- stage: this wave computes channels [8wv,8wv+8) of its lane's pt --
    {
      const int ptg = b * NPTS + tile * 64 + lane;
      const float x0 = data[ptg * 3], x1 = data[ptg * 3 + 1], x2 = data[ptg * 3 + 2];
      float a[8];
#pragma unroll
      for (int c = 0; c < 8; ++c) a[c] = b2[wv * 8 + c];   // s_load
#pragma unroll 4
      for (int j = 0; j < 64; ++j) {                       // w1/b1 uniform
        float hj = fmaf(x0, w1[j], fmaf(x1, w1[64 + j], fmaf(x2, w1[128 + j], b1[j])));
        hj = fmaxf(hj, 0.0f);
        const float* __restrict__ w2r = w2 + j * 128 + wv * 8;  // s_load x8
#pragma unroll
        for (int c = 0; c < 8; ++c) a[c] = fmaf(hj, w2r[c], a[c]);
      }
#pragma unroll
      for (int c = 0; c < 8; ++c) h2t[wv * 8 + c][lane] = fmaxf(a[c], 0.0f);
    }
    __syncthreads();

    // ---- GEMM: 64 pts (lanes) x 32 outs (this wave), k = 0..127 ----
    float acc[32];
#pragma unroll
    for (int o = 0; o < 32; ++o) acc[o] = b3[wv * 32 + o]; // s_load
#pragma unroll 2
    for (int k = 0; k < 128; ++k) {
      const float hk = h2t[k][lane];                       // ds_read_b32
      const float* __restrict__ wr = w3b + k * 512;        // uniform -> s_load
#pragma unroll
      for (int o = 0; o < 32; ++o) acc[o] = fmaf(hk, wr[o], acc[o]);
    }
#pragma unroll
    for (int o = 0; o < 32; ++o) m[o] = fmaxf(m[o], acc[o]);
    __syncthreads();                                       // h2t reuse guard
  }

  // ---- pool across the 64 point-lanes ----
#pragma unroll
  for (int off = 32; off > 0; off >>= 1) {
#pragma unroll
    for (int o = 0; o < 32; ++o) m[o] = fmaxf(m[o], __shfl_xor(m[o], off, 64));
  }
  if (lane == 0) {
    float* __restrict__ hr = henc + b * 512 + wv * 32;
#pragma unroll
    for (int o = 0; o < 32; ++o) hr[o] = m[o];
  }
}

// ---------------------------------------------------------------------------
// GRU rollout, f64 internal, h in LDS (unchanged from passing round 4 except
// the matvec load pattern): waves 0-11 read whh ROWS directly as per-lane
// float4 over k (4x fewer VMEM instructions than the dword-column walk, each
// 64B line fully consumed inside the unroll window; ascending-k single-chain
// f64 accumulation preserved bit-identically). Waves 12-15 run out_mlp
// concurrently. Drops the whT transpose + prep kernel.
// ---------------------------------------------------------------------------
__global__ __launch_bounds__(1024) void gru_kernel(
    const float* __restrict__ henc,     // [256][512]
    const float* __restrict__ mw1, const float* __restrict__ mb1,
    const float* __restrict__ mw2, const float* __restrict__ mb2,
    const float* __restrict__ mw3, const float* __restrict__ mb3,
    const float* __restrict__ wih, const float* __restrict__ whh,
    const float* __restrict__ bih, const float* __restrict__ bhh,
    const float* __restrict__ ow1, const float* __restrict__ ob1,
    const float* __restrict__ ow2, const float* __restrict__ ob2,
    const float* __restrict__ ow3, const float* __restrict__ ob3,
    float* __restrict__ dout) {
  __shared__ __align__(16) double h_l[256 * 2];   // [i][g]
  __shared__ double comb_l[768 * 2];   // bhh + Whh@h, [o][g]
  __shared__ double g1_l[256 * 2];
  __shared__ double g2_l[128 * 2];
  __shared__ double o1_l[64 * 2];
  __shared__ double o2_l[64 * 2];
  __shared__ double gia_l[12];         // gi accumulator, [g][c]
  __shared__ float wih_l[768 * 6];
  __shared__ float bih_l[768];

  const int t = threadIdx.x;
  const int s0 = blockIdx.x << 1;

  for (int i = t; i < 768 * 6; i += 1024) wih_l[i] = wih[i];
  if (t < 768) bih_l[t] = bih[t];

  // ---- phase 0: gru_h init MLP (512->256->128->256), f64 ----
  if (t < 512) {
    const int o = t & 255, g = t >> 8;
    const float* __restrict__ hrow = henc + ((s0 + g) << 9);
    double a = (double)mb1[o];
#pragma unroll 4
    for (int k = 0; k < 512; ++k)
      a = fma((double)hrow[k], (double)mw1[k * 256 + o], a);
    g1_l[o * 2 + g] = fmax(a, 0.0);
  }
  __syncthreads();
  if (t < 256) {
    const int o = t & 127, g = t >> 7;
    double a = (double)mb2[o];
#pragma unroll 4
    for (int k = 0; k < 256; ++k) a = fma(g1_l[k * 2 + g], (double)mw2[k * 128 + o], a);
    g2_l[o * 2 + g] = fmax(a, 0.0);
  }
  __syncthreads();
  if (t < 512) {
    const int o = t & 255, g = t >> 8;
    double a = (double)mb3[o];
#pragma unroll 4
    for (int k = 0; k < 128; ++k) a = fma(g2_l[k * 2 + g], (double)mw3[k * 256 + o], a);
    h_l[o * 2 + g] = a;
  }
  if (t < 12) gia_l[t] = 0.0;
  __syncthreads();

  // per-matvec-thread constants
  const double bhh_o = (t < 768) ? (double)bhh[t] : 0.0;
  const float* __restrict__ wrow = whh + (t < 768 ? t : 0) * 256;
  const int tb = t - 768;

  // ---- prologue: comb = bhh + Whh @ h0 ----
  if (t < 768) {
    double a0 = bhh_o, a1 = bhh_o;
#pragma unroll 4
    for (int k4 = 0; k4 < 64; ++k4) {
      const float4 w4 = *(const float4*)(wrow + (k4 << 2));
      const double2 h0 = *(const double2*)(h_l + ((k4 << 2) << 1));
      const double2 h1 = *(const double2*)(h_l + (((k4 << 2) + 1) << 1));
      const double2 h2 = *(const double2*)(h_l + (((k4 << 2) + 2) << 1));
      const double2 h3 = *(const double2*)(h_l + (((k4 << 2) + 3) << 1));
      a0 = fma(h0.x, (double)w4.x, a0); a1 = fma(h0.y, (double)w4.x, a1);
      a0 = fma(h1.x, (double)w4.y, a0); a1 = fma(h1.y, (double)w4.y, a1);
      a0 = fma(h2.x, (double)w4.z, a0); a1 = fma(h2.y, (double)w4.z, a1);
      a0 = fma(h3.x, (double)w4.w, a0); a1 = fma(h3.y, (double)w4.w, a1);
    }
    comb_l[t * 2 + 0] = a0; comb_l[t * 2 + 1] = a1;
  }
  __syncthreads();

  for (int step = 0; step < T_; ++step) {
    // ---- G: gates + h update (t<512); gi 6-dot folded in ----
    if (t < 512) {
      const int i = t & 255, g = t >> 8;
      double gr = (double)bih_l[i], gz = (double)bih_l[256 + i],
             gn = (double)bih_l[512 + i];
#pragma unroll
      for (int a = 0; a < 6; ++a) {
        const double xa = gia_l[g * 6 + a];
        gr = fma((double)wih_l[i * 6 + a], xa, gr);
        gz = fma((double)wih_l[(256 + i) * 6 + a], xa, gz);
        gn = fma((double)wih_l[(512 + i) * 6 + a], xa, gn);
      }
      const double rv = 1.0 / (1.0 + exp(-(comb_l[i * 2 + g] + gr)));
      const double zv = 1.0 / (1.0 + exp(-(comb_l[(256 + i) * 2 + g] + gz)));
      const double nv = tanh(fma(rv, comb_l[(512 + i) * 2 + g], gn));
      const double hp = h_l[i * 2 + g];
      h_l[i * 2 + g] = fma(zv, hp - nv, nv);
    }
    __syncthreads();

    // ---- C1/C2/C3: matvec chunks (t<768) || out_mlp stages (t>=768) ----
    double a0 = bhh_o, a1 = bhh_o;
    if (t < 768) {
#pragma unroll 4
      for (int k4 = 0; k4 < 22; ++k4) {                    // k = 0..87
        const float4 w4 = *(const float4*)(wrow + (k4 << 2));
        const double2 h0 = *(const double2*)(h_l + ((k4 << 2) << 1));
        const double2 h1 = *(const double2*)(h_l + (((k4 << 2) + 1) << 1));
        const double2 h2 = *(const double2*)(h_l + (((k4 << 2) + 2) << 1));
        const double2 h3 = *(const double2*)(h_l + (((k4 << 2) + 3) << 1));
        a0 = fma(h0.x, (double)w4.x, a0); a1 = fma(h0.y, (double)w4.x, a1);
        a0 = fma(h1.x, (double)w4.y, a0); a1 = fma(h1.y, (double)w4.y, a1);
        a0 = fma(h2.x, (double)w4.z, a0); a1 = fma(h2.y, (double)w4.z, a1);
        a0 = fma(h3.x, (double)w4.w, a0); a1 = fma(h3.y, (double)w4.w, a1);
      }
    } else if (tb < 128) {             // out_mlp layer 1 (h -> 64)
      const int j = tb & 63, g = tb >> 6;
      double a = (double)ob1[j];
#pragma unroll 4
      for (int k = 0; k < 256; ++k) a = fma(h_l[k * 2 + g], (double)ow1[k * 64 + j], a);
      o1_l[j * 2 + g] = fmax(a, 0.0);
    }
    __syncthreads();

    if (t < 768) {
#pragma unroll 4
      for (int k4 = 22; k4 < 43; ++k4) {                   // k = 88..171
        const float4 w4 = *(const float4*)(wrow + (k4 << 2));
        const double2 h0 = *(const double2*)(h_l + ((k4 << 2) << 1));
        const double2 h1 = *(const double2*)(h_l + (((k4 << 2) + 1) << 1));
        const double2 h2 = *(const double2*)(h_l + (((k4 << 2) + 2) << 1));
        const double2 h3 = *(const double2*)(h_l + (((k4 << 2) + 3) << 1));
        a0 = fma(h0.x, (double)w4.x, a0); a1 = fma(h0.y, (double)w4.x, a1);
        a0 = fma(h1.x, (double)w4.y, a0); a1 = fma(h1.y, (double)w4.y, a1);
        a0 = fma(h2.x, (double)w4.z, a0); a1 = fma(h2.y, (double)w4.z, a1);
        a0 = fma(h3.x, (double)w4.w, a0); a1 = fma(h3.y, (double)w4.w, a1);
      }
    } else if (tb < 128) {             // out_mlp layer 2 (64 -> 64)
      const int j = tb & 63, g = tb >> 6;
      double a = (double)ob2[j];
#pragma unroll 4
      for (int k = 0; k < 64; ++k) a = fma(o1_l[k * 2 + g], (double)ow2[k * 64 + j], a);
      o2_l[j * 2 + g] = fmax(a, 0.0);
    }
    __syncthreads();

    if (t < 768) {
#pragma unroll 4
      for (int k4 = 43; k4 < 64; ++k4) {                   // k = 172..255
        const float4 w4 = *(const float4*)(wrow + (k4 << 2));
        const double2 h0 = *(const double2*)(h_l + ((k4 << 2) << 1));
        const double2 h1 = *(const double2*)(h_l + (((k4 << 2) + 1) << 1));
        const double2 h2 = *(const double2*)(h_l + (((k4 << 2) + 2) << 1));
        const double2 h3 = *(const double2*)(h_l + (((k4 << 2) + 3) << 1));
        a0 = fma(h0.x, (double)w4.x, a0); a1 = fma(h0.y, (double)w4.x, a1);
        a0 = fma(h1.x, (double)w4.y, a0); a1 = fma(h1.y, (double)w4.y, a1);
        a0 = fma(h2.x, (double)w4.z, a0); a1 = fma(h2.y, (double)w4.z, a1);
        a0 = fma(h3.x, (double)w4.w, a0); a1 = fma(h3.y, (double)w4.w, a1);
      }
      comb_l[t * 2 + 0] = a0; comb_l[t * 2 + 1] = a1;
    } else if (tb < 12) {              // out_mlp layer 3 + gia + stores
      const int g = tb / 6, c = tb - g * 6;
      double a = (double)ob3[c];
#pragma unroll 4
      for (int k = 0; k < 64; ++k) a = fma(o2_l[k * 2 + g], (double)ow3[k * 6 + c], a);
      const double gi_new = gia_l[g * 6 + c] + a;
      gia_l[g * 6 + c] = gi_new;
      const int s = s0 + g;
      dout[s * 300 + step * 6 + c] = (float)a;              // dws
      dout[76800 + s * 300 + step * 6 + c] = (float)gi_new; // ws
    }
    __syncthreads();
  }
}

extern "C" void kernel_launch(void* const* d_in, const int* in_sizes, int n_in,
                              void* d_out, int out_size, void* d_ws, size_t ws_size,
                              hipStream_t stream) {
  const float* data = (const float*)d_in[0];
  // d_in[1] = horizon (always 50)
  const float* ew1 = (const float*)d_in[2];
  const float* eb1 = (const float*)d_in[3];
  const float* ew2 = (const float*)d_in[4];
  const float* eb2 = (const float*)d_in[5];
  const float* ew3 = (const float*)d_in[6];
  const float* eb3 = (const float*)d_in[7];
  const float* mw1 = (const float*)d_in[8];
  const float* mb1 = (const float*)d_in[9];
  const float* mw2 = (const float*)d_in[10];
  const float* mb2 = (const float*)d_in[11];
  const float* mw3 = (const float*)d_in[12];
  const float* mb3 = (const float*)d_in[13];
  const float* wih = (const float*)d_in[14];
  const float* whh = (const float*)d_in[15];
  const float* bih = (const float*)d_in[16];
  const float* bhh = (const float*)d_in[17];
  const float* ow1 = (const float*)d_in[18];
  const float* ob1 = (const float*)d_in[19];
  const float* ow2 = (const float*)d_in[20];
  const float* ob2 = (const float*)d_in[21];
  const float* ow3 = (const float*)d_in[22];
  const float* ob3 = (const float*)d_in[23];
  float* out = (float*)d_out;

  float* henc = (float*)d_ws;                // 524288 B

  enc_kernel<<<256, 1024, 0, stream>>>(data, ew1, eb1, ew2, eb2, ew3, eb3, henc);
  gru_kernel<<<128, 1024, 0, stream>>>(henc,
                                       mw1, mb1, mw2, mb2, mw3, mb3,
                                       wih, whh, bih, bhh,
                                       ow1, ob1, ow2, ob2, ow3, ob3,
                                       out);
}